// Round 7
// baseline (10141.863 us; speedup 1.0000x reference)
//
#include <hip/hip_runtime.h>
#include <stdint.h>

// Forbid mul+add contraction: pk_fma would change rounding vs the reference's
// separate mul/add ops. Critical scalar math also uses explicit __f*_rn.
#pragma clang fp contract(off)

typedef unsigned long long u64;
typedef unsigned int u32;
typedef float v2f __attribute__((ext_vector_type(2)));

#define BB 8
#define NN 4096
#define SS 1024
#define EE 102      // int(0.1 * 1024)
#define NBB 3072    // N - S
#define FT 256      // fps threads (4 waves, 1 per SIMD)
#define PT 16       // points per thread (contiguous: thread t owns [16t,16t+16))
#define SEL_T 512

// DPP wave64 max-reduce step (bound_ctrl: OOB lanes read 0; values >= 0).
template <int CTRL>
__device__ __forceinline__ float maxdpp(float v) {
  int m = __builtin_amdgcn_update_dpp(0, __float_as_int(v), CTRL, 0xf, 0xf, true);
  return fmaxf(v, __int_as_float(m));
}

// ---------------- FPS kernel: one block per batch ----------------
// Exact replica of _fps_order: d = (dx*dx+dy*dy)+dz*dz (no FMA), mind=min,
// argmax with lowest-index-first ties. SCALAR register arrays only (vector
// arrays get demoted to LDS — round-5 lesson). Parallel argmax: exact fmax
// tree + equality bitmask + ctz (lowest index on ties), winner coords
// broadcast through LDS alongside the key (no coord mirror, no 2nd readlane).
__global__ __launch_bounds__(FT) void fps_kernel(const float* __restrict__ x,
                                                 int* __restrict__ idxs) {
  const int b = blockIdx.x;
  const int t = threadIdx.x;
  const int w = t >> 6;
  const int lane = t & 63;
  const float* xb = x + (size_t)b * NN * 3;

  __shared__ u64 rkey[2][4];      // per-wave candidate key, double-buffered
  __shared__ float4 rcoord[2][4]; // per-wave candidate coords

  float px[PT], py[PT], pz[PT], mind[PT];

  // load 16 contiguous points = 12 float4 per thread (fully coalesced block)
  const float4* xb4 = (const float4*)xb;
  float4 f[12];
#pragma unroll
  for (int j = 0; j < 12; ++j) f[j] = xb4[t * 12 + j];
#pragma unroll
  for (int g = 0; g < 4; ++g) {
    float4 a = f[g * 3 + 0], c = f[g * 3 + 1], d = f[g * 3 + 2];
    px[g * 4 + 0] = a.x; py[g * 4 + 0] = a.y; pz[g * 4 + 0] = a.z;
    px[g * 4 + 1] = a.w; py[g * 4 + 1] = c.x; pz[g * 4 + 1] = c.y;
    px[g * 4 + 2] = c.z; py[g * 4 + 2] = c.w; pz[g * 4 + 2] = d.x;
    px[g * 4 + 3] = d.y; py[g * 4 + 3] = d.z; pz[g * 4 + 3] = d.w;
  }
#pragma unroll
  for (int q = 0; q < PT; ++q) mind[q] = __builtin_inff();

  if (t == 0) {
    idxs[(size_t)b * NN] = 0;
    // initial lp broadcast via the buf-1 slot: first overwritten at it=1,
    // which is after barrier(it=0) -> no race with this pre-loop read.
    rcoord[1][0] = make_float4(px[0], py[0], pz[0], 0.0f);
  }
  __syncthreads();
  float4 lp0 = rcoord[1][0];
  float lx = lp0.x, ly = lp0.y, lz = lp0.z;

  for (int it = 0; it < NN - 1; ++it) {
    const int buf = it & 1;
    v2f lx2, ly2, lz2;
    lx2.x = lx; lx2.y = lx; ly2.x = ly; ly2.y = ly; lz2.x = lz; lz2.y = lz;

    // phase 1: packed-f32 distances + mind update (per-half rn == scalar rn)
#pragma unroll
    for (int q = 0; q < 8; ++q) {
      v2f X; X.x = px[2 * q]; X.y = px[2 * q + 1];
      v2f Y; Y.x = py[2 * q]; Y.y = py[2 * q + 1];
      v2f Z; Z.x = pz[2 * q]; Z.y = pz[2 * q + 1];
      v2f dx = X - lx2;
      v2f dy = Y - ly2;
      v2f dz = Z - lz2;
      v2f dd = (dx * dx + dy * dy) + dz * dz;
      mind[2 * q] = fminf(mind[2 * q], dd.x);
      mind[2 * q + 1] = fminf(mind[2 * q + 1], dd.y);
    }

    // phase 2: exact thread-local max, log depth (fmax is exact -> same value
    // the reference's serial scan would produce)
    float a0 = fmaxf(mind[0], mind[1]),   a1 = fmaxf(mind[2], mind[3]);
    float a2 = fmaxf(mind[4], mind[5]),   a3 = fmaxf(mind[6], mind[7]);
    float a4 = fmaxf(mind[8], mind[9]),   a5 = fmaxf(mind[10], mind[11]);
    float a6 = fmaxf(mind[12], mind[13]), a7 = fmaxf(mind[14], mind[15]);
    float c0 = fmaxf(a0, a1), c1 = fmaxf(a2, a3);
    float c2 = fmaxf(a4, a5), c3 = fmaxf(a6, a7);
    float e0 = fmaxf(c0, c1), e1 = fmaxf(c2, c3);
    float bestv = fmaxf(e0, e1);

    // phase 2b: lowest local slot equal to the max (independent compares,
    // OR tree) -- reference tie rule: first index wins
    u32 qm = 0;
#pragma unroll
    for (int q = 0; q < PT; ++q) qm |= (mind[q] == bestv) ? (1u << q) : 0u;
    int bq = (int)__builtin_ctz(qm);

    // phase 2c: this lane's candidate coords via static cndmask tree on bq
    // (interleaves with the DPP chain below -- no serial LDS fetch later)
    const bool s0 = (bq & 1) != 0, s1 = (bq & 2) != 0,
               s2 = (bq & 4) != 0, s3 = (bq & 8) != 0;
    float e0x[8], e0y[8], e0z[8];
#pragma unroll
    for (int j = 0; j < 8; ++j) {
      e0x[j] = s0 ? px[2 * j + 1] : px[2 * j];
      e0y[j] = s0 ? py[2 * j + 1] : py[2 * j];
      e0z[j] = s0 ? pz[2 * j + 1] : pz[2 * j];
    }
    float e1x[4], e1y[4], e1z[4];
#pragma unroll
    for (int j = 0; j < 4; ++j) {
      e1x[j] = s1 ? e0x[2 * j + 1] : e0x[2 * j];
      e1y[j] = s1 ? e0y[2 * j + 1] : e0y[2 * j];
      e1z[j] = s1 ? e0z[2 * j + 1] : e0z[2 * j];
    }
    float e2x[2], e2y[2], e2z[2];
#pragma unroll
    for (int j = 0; j < 2; ++j) {
      e2x[j] = s2 ? e1x[2 * j + 1] : e1x[2 * j];
      e2y[j] = s2 ? e1y[2 * j + 1] : e1y[2 * j];
      e2z[j] = s2 ? e1z[2 * j + 1] : e1z[2 * j];
    }
    float bx = s3 ? e2x[1] : e2x[0];
    float by = s3 ? e2y[1] : e2y[0];
    float bz = s3 ? e2z[1] : e2z[0];

    // phase 3: wave64 max via DPP (VALU only), result in lane 63
    float r = bestv;
    r = maxdpp<0x111>(r);   // row_shr:1
    r = maxdpp<0x112>(r);   // row_shr:2
    r = maxdpp<0x114>(r);   // row_shr:4
    r = maxdpp<0x118>(r);   // row_shr:8
    r = maxdpp<0x142>(r);   // row_bcast:15
    r = maxdpp<0x143>(r);   // row_bcast:31
    int wmaxb = __builtin_amdgcn_readlane(__float_as_int(r), 63);

    // phase 4: first lane holding the max == lowest candidate index
    u64 msk = __ballot(__float_as_int(bestv) == wmaxb);
    int flane = (int)__builtin_ctzll(msk);
    if (lane == flane) {
      int besti = t * PT + bq;   // this lane's own best == wave winner
      rkey[buf][w] = ((u64)(u32)wmaxb << 32) | (u32)(0xFFFFFFFFu - (u32)besti);
      rcoord[buf][w] = make_float4(bx, by, bz, 0.0f);
    }
    __syncthreads();

    // phase 5: 4-way key compare (value desc, index asc packed in u64),
    // coords ride along -- no dependent LDS fetch afterwards
    u64 k0 = rkey[buf][0], k1 = rkey[buf][1];
    u64 k2 = rkey[buf][2], k3 = rkey[buf][3];
    float4 q0 = rcoord[buf][0], q1 = rcoord[buf][1];
    float4 q2 = rcoord[buf][2], q3 = rcoord[buf][3];
    bool g01 = k0 > k1;
    u64 ka2 = g01 ? k0 : k1;
    float ax2 = g01 ? q0.x : q1.x, ay2 = g01 ? q0.y : q1.y, az2 = g01 ? q0.z : q1.z;
    bool g23 = k2 > k3;
    u64 kb2 = g23 ? k2 : k3;
    float bx2 = g23 ? q2.x : q3.x, by2 = g23 ? q2.y : q3.y, bz2 = g23 ? q2.z : q3.z;
    bool gf = ka2 > kb2;
    u64 km = gf ? ka2 : kb2;
    lx = gf ? ax2 : bx2; ly = gf ? ay2 : by2; lz = gf ? az2 : bz2;
    int last = (int)(0xFFFFFFFFu - (u32)(km & 0xFFFFFFFFu));
    if (t == 0) idxs[(size_t)b * NN + it + 1] = last;
  }
}

// ------------- selection kernel: one block per batch -------------
__global__ __launch_bounds__(SEL_T) void select_kernel(const float* __restrict__ x,
                                                       const float* __restrict__ curv,
                                                       const int* __restrict__ idxs,
                                                       float* __restrict__ out) {
  const int b = blockIdx.x;
  const int t = threadIdx.x;
  __shared__ u64 ka[SS];     // sca keys: (~vbits, i)  -> ascending == desc by v
  __shared__ u64 kb[4096];   // scb keys: (vbits, i)   -> ascending, 1024 pads
  __shared__ float rmn[8], rmx[8];

  const float* cb = curv + (size_t)b * NN;
  const int* ib = idxs + (size_t)b * NN;

  float mn = __builtin_inff(), mx = -__builtin_inff();
  float cv[8];
#pragma unroll
  for (int q = 0; q < 8; ++q) {
    float v = cb[q * SEL_T + t];
    cv[q] = v;
    mn = fminf(mn, v);
    mx = fmaxf(mx, v);
  }
#pragma unroll
  for (int s = 1; s < 64; s <<= 1) {
    mn = fminf(mn, __shfl_xor(mn, s, 64));
    mx = fmaxf(mx, __shfl_xor(mx, s, 64));
  }
  if ((t & 63) == 0) { rmn[t >> 6] = mn; rmx[t >> 6] = mx; }
  __syncthreads();
  mn = rmn[0]; mx = rmx[0];
#pragma unroll
  for (int w = 1; w < 8; ++w) { mn = fminf(mn, rmn[w]); mx = fmaxf(mx, rmx[w]); }
  float denom = __fsub_rn(mx, mn);

#pragma unroll
  for (int q = 0; q < 8; ++q) {
    int i = q * SEL_T + t;
    float cn = __fdiv_rn(__fsub_rn(cv[q], mn), denom);
    int id = ib[i];
    // jnp.linspace(1,0,4096)[id] = 1 - id/4095 (true division; id=4095 -> 0)
    float sv = __fsub_rn(1.0f, __fdiv_rn((float)id, 4095.0f));
    float scv = __fmul_rn(sv, cn);   // sc >= 0 -> bits are order-monotone
    u32 vb = __float_as_uint(scv);
    if (i < SS)
      ka[i] = ((u64)(vb ^ 0xFFFFFFFFu) << 32) | (u32)i;
    else
      kb[i - SS] = ((u64)vb << 32) | (u32)(i - SS);
  }
  for (int i = NBB + t; i < 4096; i += SEL_T) kb[i] = ~0ULL;  // pads to the top
  __syncthreads();

  // bitonic sort ka ascending (n=1024, 512 pairs: one per thread)
  for (u32 k = 2; k <= SS; k <<= 1) {
    for (u32 j = k >> 1; j > 0; j >>= 1) {
      u32 p = (u32)t;
      u32 i = ((p & ~(j - 1)) << 1) | (p & (j - 1));
      u32 l = i | j;
      bool up = ((i & k) == 0);
      u64 a = ka[i], c = ka[l];
      if ((a > c) == up) { ka[i] = c; ka[l] = a; }
      __syncthreads();
    }
  }
  // bitonic sort kb ascending (n=4096, 2048 pairs: 4 per thread)
  for (u32 k = 2; k <= 4096; k <<= 1) {
    for (u32 j = k >> 1; j > 0; j >>= 1) {
#pragma unroll
      for (u32 p = (u32)t; p < 2048; p += SEL_T) {
        u32 i = ((p & ~(j - 1)) << 1) | (p & (j - 1));
        u32 l = i | j;
        bool up = ((i & k) == 0);
        u64 a = kb[i], c = kb[l];
        if ((a > c) == up) { kb[i] = c; kb[l] = a; }
      }
      __syncthreads();
    }
  }

  // final[j]: j<922 -> ba_idx[j]; else tb beats ba ? tb_idx[j] : ba_idx[j]
#pragma unroll
  for (int j0 = 0; j0 < SS; j0 += SEL_T) {
    int j = j0 + t;
    u64 A = ka[j];
    int baid = (int)(u32)(A & 0xFFFFFFFFu);
    u32 babits = ((u32)(A >> 32)) ^ 0xFFFFFFFFu;
    int fin = baid;
    if (j >= SS - EE) {
      u64 Bk = kb[2048 + j];           // largest-1024 of scb, ascending
      u32 tbbits = (u32)(Bk >> 32);
      if (tbbits > babits) fin = (int)(u32)(Bk & 0xFFFFFFFFu) + SS;
    }
    int pt = ib[fin];
    out[(size_t)b * SS + j] = (float)fin;
    const float* xp = x + ((size_t)b * NN + (size_t)pt) * 3;
    float* op = out + (size_t)BB * SS + ((size_t)b * SS + (size_t)j) * 3;
    op[0] = xp[0];
    op[1] = xp[1];
    op[2] = xp[2];
  }
}

extern "C" void kernel_launch(void* const* d_in, const int* in_sizes, int n_in,
                              void* d_out, int out_size, void* d_ws, size_t ws_size,
                              hipStream_t stream) {
  (void)in_sizes; (void)n_in; (void)out_size; (void)ws_size;
  const float* x = (const float*)d_in[0];
  const float* curv = (const float*)d_in[1];
  int* idxs = (int*)d_ws;             // B*N int32 = 128 KB scratch
  float* out = (float*)d_out;

  fps_kernel<<<BB, FT, 0, stream>>>(x, idxs);
  select_kernel<<<BB, SEL_T, 0, stream>>>(x, curv, idxs, out);
}

// Round 8
// 4118.447 us; speedup vs baseline: 2.4625x; 2.4625x over previous
//
#include <hip/hip_runtime.h>
#include <stdint.h>

// Forbid mul+add contraction: pk_fma would change rounding vs the reference's
// separate mul/add ops. Critical scalar math also uses explicit __f*_rn.
#pragma clang fp contract(off)

typedef unsigned long long u64;
typedef unsigned int u32;
typedef float v2f __attribute__((ext_vector_type(2)));

#define BB 8
#define NN 4096
#define SS 1024
#define EE 102      // int(0.1 * 1024)
#define NBB 3072    // N - S
#define FT 256      // fps threads (4 waves, 1 per SIMD)
#define PT 16       // points per thread (contiguous: thread t owns [16t,16t+16))
#define SEL_T 512

// DPP wave64 max-reduce step (bound_ctrl: OOB lanes read 0; values >= 0).
template <int CTRL>
__device__ __forceinline__ float maxdpp(float v) {
  int m = __builtin_amdgcn_update_dpp(0, __float_as_int(v), CTRL, 0xf, 0xf, true);
  return fmaxf(v, __int_as_float(m));
}

// ---------------- FPS kernel: one block per batch ----------------
// Exact replica of _fps_order: d = (dx*dx+dy*dy)+dz*dz (no FMA), mind=min,
// argmax with lowest-index-first ties. NO per-thread arrays anywhere --
// named scalars only (rounds 5/7: any array that fails SROA gets demoted to
// LDS by PromoteAlloca when LDS is free, with 2e7 bank conflicts).
__global__ __launch_bounds__(FT) void fps_kernel(const float* __restrict__ x,
                                                 int* __restrict__ idxs) {
  const int b = blockIdx.x;
  const int t = threadIdx.x;
  const int w = t >> 6;
  const int lane = t & 63;
  const float* xb = x + (size_t)b * NN * 3;

  __shared__ u64 rkey[2][4];      // per-wave candidate key, double-buffered
  __shared__ float4 rcoord[2][4]; // per-wave candidate coords

  // ---- load 16 contiguous points = 12 float4 (coalesced), all named ----
  const float4* xb4 = (const float4*)xb;
  float4 f0 = xb4[t * 12 + 0],  f1 = xb4[t * 12 + 1],  f2 = xb4[t * 12 + 2];
  float4 f3 = xb4[t * 12 + 3],  f4 = xb4[t * 12 + 4],  f5 = xb4[t * 12 + 5];
  float4 f6 = xb4[t * 12 + 6],  f7 = xb4[t * 12 + 7],  f8 = xb4[t * 12 + 8];
  float4 f9 = xb4[t * 12 + 9],  f10 = xb4[t * 12 + 10], f11 = xb4[t * 12 + 11];

  float p0x = f0.x,  p0y = f0.y,  p0z = f0.z;
  float p1x = f0.w,  p1y = f1.x,  p1z = f1.y;
  float p2x = f1.z,  p2y = f1.w,  p2z = f2.x;
  float p3x = f2.y,  p3y = f2.z,  p3z = f2.w;
  float p4x = f3.x,  p4y = f3.y,  p4z = f3.z;
  float p5x = f3.w,  p5y = f4.x,  p5z = f4.y;
  float p6x = f4.z,  p6y = f4.w,  p6z = f5.x;
  float p7x = f5.y,  p7y = f5.z,  p7z = f5.w;
  float p8x = f6.x,  p8y = f6.y,  p8z = f6.z;
  float p9x = f6.w,  p9y = f7.x,  p9z = f7.y;
  float p10x = f7.z, p10y = f7.w, p10z = f8.x;
  float p11x = f8.y, p11y = f8.z, p11z = f8.w;
  float p12x = f9.x, p12y = f9.y, p12z = f9.z;
  float p13x = f9.w, p13y = f10.x, p13z = f10.y;
  float p14x = f10.z, p14y = f10.w, p14z = f11.x;
  float p15x = f11.y, p15y = f11.z, p15z = f11.w;

  const float INF = __builtin_inff();
  float d0 = INF, d1 = INF, d2 = INF, d3 = INF, d4 = INF, d5 = INF,
        d6 = INF, d7 = INF, d8 = INF, d9 = INF, d10 = INF, d11 = INF,
        d12 = INF, d13 = INF, d14 = INF, d15 = INF;

  if (t == 0) {
    idxs[(size_t)b * NN] = 0;
    // initial lp via buf-1 slot: first overwritten at it=1 (after barrier 0)
    rcoord[1][0] = make_float4(p0x, p0y, p0z, 0.0f);
  }
  __syncthreads();
  float4 lp0 = rcoord[1][0];
  float lx = lp0.x, ly = lp0.y, lz = lp0.z;

  for (int it = 0; it < NN - 1; ++it) {
    const int buf = it & 1;
    v2f lx2; lx2.x = lx; lx2.y = lx;
    v2f ly2; ly2.x = ly; ly2.y = ly;
    v2f lz2; lz2.x = lz; lz2.y = lz;

    // phase 1: packed-f32 distances + mind update (per-half rn == scalar rn)
#define DPAIR(i, j)                                   \
    do {                                              \
      v2f X; X.x = p##i##x; X.y = p##j##x;            \
      v2f Y; Y.x = p##i##y; Y.y = p##j##y;            \
      v2f Z; Z.x = p##i##z; Z.y = p##j##z;            \
      v2f dx = X - lx2;                               \
      v2f dy = Y - ly2;                               \
      v2f dz = Z - lz2;                               \
      v2f dd = (dx * dx + dy * dy) + dz * dz;         \
      d##i = fminf(d##i, dd.x);                       \
      d##j = fminf(d##j, dd.y);                       \
    } while (0)
    DPAIR(0, 1); DPAIR(2, 3); DPAIR(4, 5); DPAIR(6, 7);
    DPAIR(8, 9); DPAIR(10, 11); DPAIR(12, 13); DPAIR(14, 15);
#undef DPAIR

    // phase 2: exact thread-local max, log depth
    float a0 = fmaxf(d0, d1),   a1 = fmaxf(d2, d3);
    float a2 = fmaxf(d4, d5),   a3 = fmaxf(d6, d7);
    float a4 = fmaxf(d8, d9),   a5 = fmaxf(d10, d11);
    float a6 = fmaxf(d12, d13), a7 = fmaxf(d14, d15);
    float c0 = fmaxf(a0, a1), c1 = fmaxf(a2, a3);
    float c2 = fmaxf(a4, a5), c3 = fmaxf(a6, a7);
    float g0 = fmaxf(c0, c1), g1 = fmaxf(c2, c3);
    float bestv = fmaxf(g0, g1);

    // phase 2b: lowest local slot equal to max (ties -> first index, as ref)
    u32 qm = (d0 == bestv ? 0x0001u : 0u) | (d1 == bestv ? 0x0002u : 0u) |
             (d2 == bestv ? 0x0004u : 0u) | (d3 == bestv ? 0x0008u : 0u) |
             (d4 == bestv ? 0x0010u : 0u) | (d5 == bestv ? 0x0020u : 0u) |
             (d6 == bestv ? 0x0040u : 0u) | (d7 == bestv ? 0x0080u : 0u) |
             (d8 == bestv ? 0x0100u : 0u) | (d9 == bestv ? 0x0200u : 0u) |
             (d10 == bestv ? 0x0400u : 0u) | (d11 == bestv ? 0x0800u : 0u) |
             (d12 == bestv ? 0x1000u : 0u) | (d13 == bestv ? 0x2000u : 0u) |
             (d14 == bestv ? 0x4000u : 0u) | (d15 == bestv ? 0x8000u : 0u);
    int bq = (int)__builtin_ctz(qm);

    // phase 2c: candidate coords via static cndmask tree on bq's bits
    const bool s0 = (bq & 1) != 0, s1 = (bq & 2) != 0,
               s2 = (bq & 4) != 0, s3 = (bq & 8) != 0;
    float e0x0 = s0 ? p1x : p0x,  e0y0 = s0 ? p1y : p0y,  e0z0 = s0 ? p1z : p0z;
    float e0x1 = s0 ? p3x : p2x,  e0y1 = s0 ? p3y : p2y,  e0z1 = s0 ? p3z : p2z;
    float e0x2 = s0 ? p5x : p4x,  e0y2 = s0 ? p5y : p4y,  e0z2 = s0 ? p5z : p4z;
    float e0x3 = s0 ? p7x : p6x,  e0y3 = s0 ? p7y : p6y,  e0z3 = s0 ? p7z : p6z;
    float e0x4 = s0 ? p9x : p8x,  e0y4 = s0 ? p9y : p8y,  e0z4 = s0 ? p9z : p8z;
    float e0x5 = s0 ? p11x : p10x, e0y5 = s0 ? p11y : p10y, e0z5 = s0 ? p11z : p10z;
    float e0x6 = s0 ? p13x : p12x, e0y6 = s0 ? p13y : p12y, e0z6 = s0 ? p13z : p12z;
    float e0x7 = s0 ? p15x : p14x, e0y7 = s0 ? p15y : p14y, e0z7 = s0 ? p15z : p14z;
    float e1x0 = s1 ? e0x1 : e0x0, e1y0 = s1 ? e0y1 : e0y0, e1z0 = s1 ? e0z1 : e0z0;
    float e1x1 = s1 ? e0x3 : e0x2, e1y1 = s1 ? e0y3 : e0y2, e1z1 = s1 ? e0z3 : e0z2;
    float e1x2 = s1 ? e0x5 : e0x4, e1y2 = s1 ? e0y5 : e0y4, e1z2 = s1 ? e0z5 : e0z4;
    float e1x3 = s1 ? e0x7 : e0x6, e1y3 = s1 ? e0y7 : e0y6, e1z3 = s1 ? e0z7 : e0z6;
    float e2x0 = s2 ? e1x1 : e1x0, e2y0 = s2 ? e1y1 : e1y0, e2z0 = s2 ? e1z1 : e1z0;
    float e2x1 = s2 ? e1x3 : e1x2, e2y1 = s2 ? e1y3 : e1y2, e2z1 = s2 ? e1z3 : e1z2;
    float bx = s3 ? e2x1 : e2x0;
    float by = s3 ? e2y1 : e2y0;
    float bz = s3 ? e2z1 : e2z0;

    // phase 3: wave64 max via DPP (VALU only), result in lane 63
    float r = bestv;
    r = maxdpp<0x111>(r);   // row_shr:1
    r = maxdpp<0x112>(r);   // row_shr:2
    r = maxdpp<0x114>(r);   // row_shr:4
    r = maxdpp<0x118>(r);   // row_shr:8
    r = maxdpp<0x142>(r);   // row_bcast:15
    r = maxdpp<0x143>(r);   // row_bcast:31
    int wmaxb = __builtin_amdgcn_readlane(__float_as_int(r), 63);

    // phase 4: first lane holding the max == lowest candidate index
    u64 msk = __ballot(__float_as_int(bestv) == wmaxb);
    int flane = (int)__builtin_ctzll(msk);
    if (lane == flane) {
      int besti = t * PT + bq;   // this lane's own best == wave winner
      rkey[buf][w] = ((u64)(u32)wmaxb << 32) | (u32)(0xFFFFFFFFu - (u32)besti);
      rcoord[buf][w] = make_float4(bx, by, bz, 0.0f);
    }
    __syncthreads();

    // phase 5: 4-way key compare; coords ride along (no dependent LDS fetch)
    u64 k0 = rkey[buf][0], k1 = rkey[buf][1];
    u64 k2 = rkey[buf][2], k3 = rkey[buf][3];
    float4 q0 = rcoord[buf][0], q1 = rcoord[buf][1];
    float4 q2 = rcoord[buf][2], q3 = rcoord[buf][3];
    bool g01 = k0 > k1;
    u64 ka2 = g01 ? k0 : k1;
    float ax2 = g01 ? q0.x : q1.x, ay2 = g01 ? q0.y : q1.y, az2 = g01 ? q0.z : q1.z;
    bool g23 = k2 > k3;
    u64 kb2 = g23 ? k2 : k3;
    float bx2 = g23 ? q2.x : q3.x, by2 = g23 ? q2.y : q3.y, bz2 = g23 ? q2.z : q3.z;
    bool gf = ka2 > kb2;
    u64 km = gf ? ka2 : kb2;
    lx = gf ? ax2 : bx2; ly = gf ? ay2 : by2; lz = gf ? az2 : bz2;
    int last = (int)(0xFFFFFFFFu - (u32)(km & 0xFFFFFFFFu));
    if (t == 0) idxs[(size_t)b * NN + it + 1] = last;
  }
}

// ------------- selection kernel: one block per batch -------------
__global__ __launch_bounds__(SEL_T) void select_kernel(const float* __restrict__ x,
                                                       const float* __restrict__ curv,
                                                       const int* __restrict__ idxs,
                                                       float* __restrict__ out) {
  const int b = blockIdx.x;
  const int t = threadIdx.x;
  __shared__ u64 ka[SS];     // sca keys: (~vbits, i)  -> ascending == desc by v
  __shared__ u64 kb[4096];   // scb keys: (vbits, i)   -> ascending, 1024 pads
  __shared__ float rmn[8], rmx[8];

  const float* cb = curv + (size_t)b * NN;
  const int* ib = idxs + (size_t)b * NN;

  float mn = __builtin_inff(), mx = -__builtin_inff();
  float cv[8];
#pragma unroll
  for (int q = 0; q < 8; ++q) {
    float v = cb[q * SEL_T + t];
    cv[q] = v;
    mn = fminf(mn, v);
    mx = fmaxf(mx, v);
  }
#pragma unroll
  for (int s = 1; s < 64; s <<= 1) {
    mn = fminf(mn, __shfl_xor(mn, s, 64));
    mx = fmaxf(mx, __shfl_xor(mx, s, 64));
  }
  if ((t & 63) == 0) { rmn[t >> 6] = mn; rmx[t >> 6] = mx; }
  __syncthreads();
  mn = rmn[0]; mx = rmx[0];
#pragma unroll
  for (int w = 1; w < 8; ++w) { mn = fminf(mn, rmn[w]); mx = fmaxf(mx, rmx[w]); }
  float denom = __fsub_rn(mx, mn);

#pragma unroll
  for (int q = 0; q < 8; ++q) {
    int i = q * SEL_T + t;
    float cn = __fdiv_rn(__fsub_rn(cv[q], mn), denom);
    int id = ib[i];
    // jnp.linspace(1,0,4096)[id] = 1 - id/4095 (true division; id=4095 -> 0)
    float sv = __fsub_rn(1.0f, __fdiv_rn((float)id, 4095.0f));
    float scv = __fmul_rn(sv, cn);   // sc >= 0 -> bits are order-monotone
    u32 vb = __float_as_uint(scv);
    if (i < SS)
      ka[i] = ((u64)(vb ^ 0xFFFFFFFFu) << 32) | (u32)i;
    else
      kb[i - SS] = ((u64)vb << 32) | (u32)(i - SS);
  }
  for (int i = NBB + t; i < 4096; i += SEL_T) kb[i] = ~0ULL;  // pads to the top
  __syncthreads();

  // bitonic sort ka ascending (n=1024, 512 pairs: one per thread)
  for (u32 k = 2; k <= SS; k <<= 1) {
    for (u32 j = k >> 1; j > 0; j >>= 1) {
      u32 p = (u32)t;
      u32 i = ((p & ~(j - 1)) << 1) | (p & (j - 1));
      u32 l = i | j;
      bool up = ((i & k) == 0);
      u64 a = ka[i], c = ka[l];
      if ((a > c) == up) { ka[i] = c; ka[l] = a; }
      __syncthreads();
    }
  }
  // bitonic sort kb ascending (n=4096, 2048 pairs: 4 per thread)
  for (u32 k = 2; k <= 4096; k <<= 1) {
    for (u32 j = k >> 1; j > 0; j >>= 1) {
#pragma unroll
      for (u32 p = (u32)t; p < 2048; p += SEL_T) {
        u32 i = ((p & ~(j - 1)) << 1) | (p & (j - 1));
        u32 l = i | j;
        bool up = ((i & k) == 0);
        u64 a = kb[i], c = kb[l];
        if ((a > c) == up) { kb[i] = c; kb[l] = a; }
      }
      __syncthreads();
    }
  }

  // final[j]: j<922 -> ba_idx[j]; else tb beats ba ? tb_idx[j] : ba_idx[j]
#pragma unroll
  for (int j0 = 0; j0 < SS; j0 += SEL_T) {
    int j = j0 + t;
    u64 A = ka[j];
    int baid = (int)(u32)(A & 0xFFFFFFFFu);
    u32 babits = ((u32)(A >> 32)) ^ 0xFFFFFFFFu;
    int fin = baid;
    if (j >= SS - EE) {
      u64 Bk = kb[2048 + j];           // largest-1024 of scb, ascending
      u32 tbbits = (u32)(Bk >> 32);
      if (tbbits > babits) fin = (int)(u32)(Bk & 0xFFFFFFFFu) + SS;
    }
    int pt = ib[fin];
    out[(size_t)b * SS + j] = (float)fin;
    const float* xp = x + ((size_t)b * NN + (size_t)pt) * 3;
    float* op = out + (size_t)BB * SS + ((size_t)b * SS + (size_t)j) * 3;
    op[0] = xp[0];
    op[1] = xp[1];
    op[2] = xp[2];
  }
}

extern "C" void kernel_launch(void* const* d_in, const int* in_sizes, int n_in,
                              void* d_out, int out_size, void* d_ws, size_t ws_size,
                              hipStream_t stream) {
  (void)in_sizes; (void)n_in; (void)out_size; (void)ws_size;
  const float* x = (const float*)d_in[0];
  const float* curv = (const float*)d_in[1];
  int* idxs = (int*)d_ws;             // B*N int32 = 128 KB scratch
  float* out = (float*)d_out;

  fps_kernel<<<BB, FT, 0, stream>>>(x, idxs);
  select_kernel<<<BB, SEL_T, 0, stream>>>(x, curv, idxs, out);
}

// Round 9
// 2489.565 us; speedup vs baseline: 4.0737x; 1.6543x over previous
//
#include <hip/hip_runtime.h>
#include <stdint.h>

// Forbid mul+add contraction: pk_fma would change rounding vs the reference's
// separate mul/add ops. Critical scalar math also uses explicit __f*_rn.
#pragma clang fp contract(off)

typedef unsigned long long u64;
typedef unsigned int u32;
typedef float v2f __attribute__((ext_vector_type(2)));

#define BB 8
#define NN 4096
#define SS 1024
#define EE 102      // int(0.1 * 1024)
#define NBB 3072    // N - S
#define FT 256      // fps threads (4 waves, 1 per SIMD)
#define PT 16       // points per thread (contiguous: thread t owns [16t,16t+16))
#define SEL_T 512

// DPP wave64 max-reduce step (bound_ctrl: OOB lanes read 0; values >= 0).
template <int CTRL>
__device__ __forceinline__ float maxdpp(float v) {
  int m = __builtin_amdgcn_update_dpp(0, __float_as_int(v), CTRL, 0xf, 0xf, true);
  return fmaxf(v, __int_as_float(m));
}

// ---------------- FPS kernel: one block per batch ----------------
// Exact replica of _fps_order: d = (dx*dx+dy*dy)+dz*dz (no FMA), mind=min,
// argmax with lowest-index-first ties. Round-6 proven base (scalar arrays +
// 64KB lxyz mirror -- the mirror also shields the arrays from PromoteAlloca
// demotion, rounds 5/7/8 lesson). New: each lane prefetches its OWN
// candidate's coords (lxyz[t*16+bq]) right after local argmax -- latency
// hides under the DPP chain -- and the winning lane publishes coords+key;
// kills the dependent post-reduce lxyz[last] read and the 2nd readlane.
__global__ __launch_bounds__(FT) void fps_kernel(const float* __restrict__ x,
                                                 int* __restrict__ idxs) {
  const int b = blockIdx.x;
  const int t = threadIdx.x;
  const int w = t >> 6;
  const int lane = t & 63;
  const float* xb = x + (size_t)b * NN * 3;

  __shared__ float4 lxyz[NN];     // 64 KB coord mirror (+ demotion shield)
  __shared__ u64 rkey[2][4];      // per-wave candidate key, double-buffered
  __shared__ float4 rcoord[2][4]; // per-wave candidate coords

  float px[PT], py[PT], pz[PT], mind[PT];

  // load 16 contiguous points = 12 float4 per thread (fully coalesced block)
  const float4* xb4 = (const float4*)xb;
  float4 f[12];
#pragma unroll
  for (int j = 0; j < 12; ++j) f[j] = xb4[t * 12 + j];
#pragma unroll
  for (int g = 0; g < 4; ++g) {
    float4 a = f[g * 3 + 0], c = f[g * 3 + 1], d = f[g * 3 + 2];
    px[g * 4 + 0] = a.x; py[g * 4 + 0] = a.y; pz[g * 4 + 0] = a.z;
    px[g * 4 + 1] = a.w; py[g * 4 + 1] = c.x; pz[g * 4 + 1] = c.y;
    px[g * 4 + 2] = c.z; py[g * 4 + 2] = c.w; pz[g * 4 + 2] = d.x;
    px[g * 4 + 3] = d.y; py[g * 4 + 3] = d.z; pz[g * 4 + 3] = d.w;
  }
#pragma unroll
  for (int q = 0; q < PT; ++q) {
    lxyz[t * PT + q] = make_float4(px[q], py[q], pz[q], 0.0f);
    mind[q] = __builtin_inff();
  }
  if (t == 0) {
    idxs[(size_t)b * NN] = 0;
    // initial lp via buf-1 slot: first overwritten at it=1 (after barrier 0)
    rcoord[1][0] = make_float4(px[0], py[0], pz[0], 0.0f);
  }
  __syncthreads();
  float4 lp0 = rcoord[1][0];
  float lx = lp0.x, ly = lp0.y, lz = lp0.z;

  for (int it = 0; it < NN - 1; ++it) {
    const int buf = it & 1;
    v2f lx2; lx2.x = lx; lx2.y = lx;
    v2f ly2; ly2.x = ly; ly2.y = ly;
    v2f lz2; lz2.x = lz; lz2.y = lz;

    // phase 1: packed-f32 distances + mind update + serial lowest-index
    // select (round-6 proven; per-half rn rounding == scalar rn)
    float bestv = -1.0f;
    int bq = 0;
#pragma unroll
    for (int q = 0; q < 8; ++q) {
      v2f X; X.x = px[2 * q]; X.y = px[2 * q + 1];
      v2f Y; Y.x = py[2 * q]; Y.y = py[2 * q + 1];
      v2f Z; Z.x = pz[2 * q]; Z.y = pz[2 * q + 1];
      v2f dx = X - lx2;
      v2f dy = Y - ly2;
      v2f dz = Z - lz2;
      v2f dd = (dx * dx + dy * dy) + dz * dz;
      float m0 = fminf(mind[2 * q], dd.x);
      float m1 = fminf(mind[2 * q + 1], dd.y);
      mind[2 * q] = m0;
      mind[2 * q + 1] = m1;
      // ascending q => ascending global index; strict '>' keeps lowest index
      if (m0 > bestv) { bestv = m0; bq = 2 * q; }
      if (m1 > bestv) { bestv = m1; bq = 2 * q + 1; }
    }

    // phase 1b: prefetch this lane's candidate coords from the mirror --
    // issued ~200 cyc before use, hides under DPP + ballot below
    float4 cand = lxyz[t * PT + bq];

    // phase 2: wave64 max via DPP (all VALU), result in lane 63
    float r = bestv;
    r = maxdpp<0x111>(r);   // row_shr:1
    r = maxdpp<0x112>(r);   // row_shr:2
    r = maxdpp<0x114>(r);   // row_shr:4
    r = maxdpp<0x118>(r);   // row_shr:8
    r = maxdpp<0x142>(r);   // row_bcast:15
    r = maxdpp<0x143>(r);   // row_bcast:31
    int wmaxb = __builtin_amdgcn_readlane(__float_as_int(r), 63);

    // phase 3: first lane holding the max == lowest candidate index;
    // that lane publishes its own key AND its prefetched coords
    u64 msk = __ballot(__float_as_int(bestv) == wmaxb);
    int flane = (int)__builtin_ctzll(msk);
    if (lane == flane) {
      int besti = t * PT + bq;
      rkey[buf][w] = ((u64)(u32)wmaxb << 32) | (u32)(0xFFFFFFFFu - (u32)besti);
      rcoord[buf][w] = cand;
    }
    __syncthreads();

    // phase 4: 4-way key compare (value desc, index asc packed in u64);
    // coords ride along -- no dependent LDS fetch afterwards
    u64 k0 = rkey[buf][0], k1 = rkey[buf][1];
    u64 k2 = rkey[buf][2], k3 = rkey[buf][3];
    float4 q0 = rcoord[buf][0], q1 = rcoord[buf][1];
    float4 q2 = rcoord[buf][2], q3 = rcoord[buf][3];
    bool g01 = k0 > k1;
    u64 ka2 = g01 ? k0 : k1;
    float ax2 = g01 ? q0.x : q1.x, ay2 = g01 ? q0.y : q1.y, az2 = g01 ? q0.z : q1.z;
    bool g23 = k2 > k3;
    u64 kb2 = g23 ? k2 : k3;
    float bx2 = g23 ? q2.x : q3.x, by2 = g23 ? q2.y : q3.y, bz2 = g23 ? q2.z : q3.z;
    bool gf = ka2 > kb2;
    u64 km = gf ? ka2 : kb2;
    lx = gf ? ax2 : bx2; ly = gf ? ay2 : by2; lz = gf ? az2 : bz2;
    int last = (int)(0xFFFFFFFFu - (u32)(km & 0xFFFFFFFFu));
    if (t == 0) idxs[(size_t)b * NN + it + 1] = last;
  }
}

// ------------- selection kernel: one block per batch -------------
__global__ __launch_bounds__(SEL_T) void select_kernel(const float* __restrict__ x,
                                                       const float* __restrict__ curv,
                                                       const int* __restrict__ idxs,
                                                       float* __restrict__ out) {
  const int b = blockIdx.x;
  const int t = threadIdx.x;
  __shared__ u64 ka[SS];     // sca keys: (~vbits, i)  -> ascending == desc by v
  __shared__ u64 kb[4096];   // scb keys: (vbits, i)   -> ascending, 1024 pads
  __shared__ float rmn[8], rmx[8];

  const float* cb = curv + (size_t)b * NN;
  const int* ib = idxs + (size_t)b * NN;

  float mn = __builtin_inff(), mx = -__builtin_inff();
  float cv[8];
#pragma unroll
  for (int q = 0; q < 8; ++q) {
    float v = cb[q * SEL_T + t];
    cv[q] = v;
    mn = fminf(mn, v);
    mx = fmaxf(mx, v);
  }
#pragma unroll
  for (int s = 1; s < 64; s <<= 1) {
    mn = fminf(mn, __shfl_xor(mn, s, 64));
    mx = fmaxf(mx, __shfl_xor(mx, s, 64));
  }
  if ((t & 63) == 0) { rmn[t >> 6] = mn; rmx[t >> 6] = mx; }
  __syncthreads();
  mn = rmn[0]; mx = rmx[0];
#pragma unroll
  for (int w = 1; w < 8; ++w) { mn = fminf(mn, rmn[w]); mx = fmaxf(mx, rmx[w]); }
  float denom = __fsub_rn(mx, mn);

#pragma unroll
  for (int q = 0; q < 8; ++q) {
    int i = q * SEL_T + t;
    float cn = __fdiv_rn(__fsub_rn(cv[q], mn), denom);
    int id = ib[i];
    // jnp.linspace(1,0,4096)[id] = 1 - id/4095 (true division; id=4095 -> 0)
    float sv = __fsub_rn(1.0f, __fdiv_rn((float)id, 4095.0f));
    float scv = __fmul_rn(sv, cn);   // sc >= 0 -> bits are order-monotone
    u32 vb = __float_as_uint(scv);
    if (i < SS)
      ka[i] = ((u64)(vb ^ 0xFFFFFFFFu) << 32) | (u32)i;
    else
      kb[i - SS] = ((u64)vb << 32) | (u32)(i - SS);
  }
  for (int i = NBB + t; i < 4096; i += SEL_T) kb[i] = ~0ULL;  // pads to the top
  __syncthreads();

  // bitonic sort ka ascending (n=1024, 512 pairs: one per thread)
  for (u32 k = 2; k <= SS; k <<= 1) {
    for (u32 j = k >> 1; j > 0; j >>= 1) {
      u32 p = (u32)t;
      u32 i = ((p & ~(j - 1)) << 1) | (p & (j - 1));
      u32 l = i | j;
      bool up = ((i & k) == 0);
      u64 a = ka[i], c = ka[l];
      if ((a > c) == up) { ka[i] = c; ka[l] = a; }
      __syncthreads();
    }
  }
  // bitonic sort kb ascending (n=4096, 2048 pairs: 4 per thread)
  for (u32 k = 2; k <= 4096; k <<= 1) {
    for (u32 j = k >> 1; j > 0; j >>= 1) {
#pragma unroll
      for (u32 p = (u32)t; p < 2048; p += SEL_T) {
        u32 i = ((p & ~(j - 1)) << 1) | (p & (j - 1));
        u32 l = i | j;
        bool up = ((i & k) == 0);
        u64 a = kb[i], c = kb[l];
        if ((a > c) == up) { kb[i] = c; kb[l] = a; }
      }
      __syncthreads();
    }
  }

  // final[j]: j<922 -> ba_idx[j]; else tb beats ba ? tb_idx[j] : ba_idx[j]
#pragma unroll
  for (int j0 = 0; j0 < SS; j0 += SEL_T) {
    int j = j0 + t;
    u64 A = ka[j];
    int baid = (int)(u32)(A & 0xFFFFFFFFu);
    u32 babits = ((u32)(A >> 32)) ^ 0xFFFFFFFFu;
    int fin = baid;
    if (j >= SS - EE) {
      u64 Bk = kb[2048 + j];           // largest-1024 of scb, ascending
      u32 tbbits = (u32)(Bk >> 32);
      if (tbbits > babits) fin = (int)(u32)(Bk & 0xFFFFFFFFu) + SS;
    }
    int pt = ib[fin];
    out[(size_t)b * SS + j] = (float)fin;
    const float* xp = x + ((size_t)b * NN + (size_t)pt) * 3;
    float* op = out + (size_t)BB * SS + ((size_t)b * SS + (size_t)j) * 3;
    op[0] = xp[0];
    op[1] = xp[1];
    op[2] = xp[2];
  }
}

extern "C" void kernel_launch(void* const* d_in, const int* in_sizes, int n_in,
                              void* d_out, int out_size, void* d_ws, size_t ws_size,
                              hipStream_t stream) {
  (void)in_sizes; (void)n_in; (void)out_size; (void)ws_size;
  const float* x = (const float*)d_in[0];
  const float* curv = (const float*)d_in[1];
  int* idxs = (int*)d_ws;             // B*N int32 = 128 KB scratch
  float* out = (float*)d_out;

  fps_kernel<<<BB, FT, 0, stream>>>(x, idxs);
  select_kernel<<<BB, SEL_T, 0, stream>>>(x, curv, idxs, out);
}